// Round 1
// baseline (164.999 us; speedup 1.0000x reference)
//
#include <hip/hip_runtime.h>
#include <math.h>

#define HH 4096
#define OO 4096
#define MAXLEN 2048

__device__ inline float wave_sum(float v) {
#pragma unroll
    for (int off = 32; off; off >>= 1) v += __shfl_down(v, off, 64);
    return v;
}
__device__ inline float wave_max(float v) {
#pragma unroll
    for (int off = 32; off; off >>= 1) v = fmaxf(v, __shfl_down(v, off, 64));
    return v;
}

// at_in = [emb_row | h0]; comb = [emb_row | 0 (filled later)]
__global__ void k_setup(const int* __restrict__ idx, const float* __restrict__ emb_W,
                        const float* __restrict__ hidden,
                        float* __restrict__ at_in, float* __restrict__ comb) {
    int i = blockIdx.x * 256 + threadIdx.x;   // 0..4095
    int id = idx[0];
    float e = emb_W[(size_t)id * OO + i];
    at_in[i]      = e;
    at_in[HH + i] = hidden[i];
    comb[i]       = e;
    comb[HH + i]  = 0.0f;
}

// y[row] = act(dot(W[row,:], x) + b[row]); one wave per row, float4 loads.
template <int L, int ACT>
__global__ void k_gemv(const float* __restrict__ W, const float* __restrict__ x,
                       const float* __restrict__ b, float* __restrict__ y, int nrows) {
    int wid = threadIdx.x >> 6, lane = threadIdx.x & 63;
    int row = blockIdx.x * 4 + wid;
    if (row >= nrows) return;
    const float4* Wr = (const float4*)(W + (size_t)row * L);
    const float4* xv = (const float4*)x;
    float acc = 0.f;
    for (int i = lane; i < L / 4; i += 64) {
        float4 w4 = Wr[i], x4 = xv[i];
        acc = fmaf(w4.x, x4.x, acc);
        acc = fmaf(w4.y, x4.y, acc);
        acc = fmaf(w4.z, x4.z, acc);
        acc = fmaf(w4.w, x4.w, acc);
    }
    acc = wave_sum(acc);
    if (lane == 0) {
        float r = acc + b[row];
        if (ACT) r = fmaxf(r, 0.f);
        y[row] = r;
    }
}

// softmax over 2048 logits, one block of 256 threads (8 elems/thread)
__global__ void k_softmax2048(const float* __restrict__ l, float* __restrict__ w) {
    __shared__ float red[4];
    __shared__ float bval;
    int t = threadIdx.x;
    float v[8];
    float m = -INFINITY;
#pragma unroll
    for (int j = 0; j < 8; ++j) { v[j] = l[t + 256 * j]; m = fmaxf(m, v[j]); }
    m = wave_max(m);
    if ((t & 63) == 0) red[t >> 6] = m;
    __syncthreads();
    if (t == 0) bval = fmaxf(fmaxf(red[0], red[1]), fmaxf(red[2], red[3]));
    __syncthreads();
    float mx = bval;
    float s = 0.f;
#pragma unroll
    for (int j = 0; j < 8; ++j) { v[j] = expf(v[j] - mx); s += v[j]; }
    s = wave_sum(s);
    if ((t & 63) == 0) red[t >> 6] = s;
    __syncthreads();
    if (t == 0) bval = red[0] + red[1] + red[2] + red[3];
    __syncthreads();
    float inv = 1.0f / bval;
#pragma unroll
    for (int j = 0; j < 8; ++j) w[t + 256 * j] = v[j] * inv;
}

// partial column-sums: chunk of 16 rows of encoder_outputs weighted by w
__global__ void k_attapply_part(const float* __restrict__ w, const float* __restrict__ E,
                                float* __restrict__ part) {
    int t = threadIdx.x;           // 256 threads * float4 = 4096 cols
    int chunk = blockIdx.x;        // 128 chunks * 16 rows
    float4 acc = {0.f, 0.f, 0.f, 0.f};
    for (int r = 0; r < 16; ++r) {
        int m = chunk * 16 + r;
        float wm = w[m];
        float4 e = ((const float4*)(E + (size_t)m * HH))[t];
        acc.x = fmaf(wm, e.x, acc.x);
        acc.y = fmaf(wm, e.y, acc.y);
        acc.z = fmaf(wm, e.z, acc.z);
        acc.w = fmaf(wm, e.w, acc.w);
    }
    ((float4*)(part + (size_t)chunk * HH))[t] = acc;
}

// deterministic reduce of 128 partials -> comb[4096..8191]
__global__ void k_attapply_red(const float* __restrict__ part, float* __restrict__ out) {
    int j = blockIdx.x * 256 + threadIdx.x;   // 0..4095
    float s = 0.f;
    for (int r = 0; r < 128; ++r) s += part[(size_t)r * HH + j];
    out[j] = s;
}

// fallback (small ws): weighted accumulate via atomics into comb[4096..] (pre-zeroed)
__global__ void k_attapply_atomic(const float* __restrict__ w, const float* __restrict__ E,
                                  float* __restrict__ out) {
    int t = threadIdx.x;
    int chunk = blockIdx.x;
    float4 acc = {0.f, 0.f, 0.f, 0.f};
    for (int r = 0; r < 16; ++r) {
        int m = chunk * 16 + r;
        float wm = w[m];
        float4 e = ((const float4*)(E + (size_t)m * HH))[t];
        acc.x = fmaf(wm, e.x, acc.x);
        acc.y = fmaf(wm, e.y, acc.y);
        acc.z = fmaf(wm, e.z, acc.z);
        acc.w = fmaf(wm, e.w, acc.w);
    }
    atomicAdd(&out[t * 4 + 0], acc.x);
    atomicAdd(&out[t * 4 + 1], acc.y);
    atomicAdd(&out[t * 4 + 2], acc.z);
    atomicAdd(&out[t * 4 + 3], acc.w);
}

// GRU gate math; h_new written straight into d_out[H..2H)
__global__ void k_gru(const float* __restrict__ gi, const float* __restrict__ gh,
                      const float* __restrict__ h, float* __restrict__ h_new) {
    int i = blockIdx.x * 256 + threadIdx.x;
    float r = 1.f / (1.f + expf(-(gi[i] + gh[i])));
    float z = 1.f / (1.f + expf(-(gi[HH + i] + gh[HH + i])));
    float n = tanhf(gi[2 * HH + i] + r * gh[2 * HH + i]);
    h_new[i] = (1.f - z) * n + z * h[i];
}

// log_softmax over 4096, one block of 256 threads (16 elems/thread)
__global__ void k_logsoftmax4096(const float* __restrict__ l, float* __restrict__ out) {
    __shared__ float red[4];
    __shared__ float bval;
    int t = threadIdx.x;
    float v[16];
    float m = -INFINITY;
#pragma unroll
    for (int j = 0; j < 16; ++j) { v[j] = l[t + 256 * j]; m = fmaxf(m, v[j]); }
    m = wave_max(m);
    if ((t & 63) == 0) red[t >> 6] = m;
    __syncthreads();
    if (t == 0) bval = fmaxf(fmaxf(red[0], red[1]), fmaxf(red[2], red[3]));
    __syncthreads();
    float mx = bval;
    float s = 0.f;
#pragma unroll
    for (int j = 0; j < 16; ++j) s += expf(v[j] - mx);
    s = wave_sum(s);
    if ((t & 63) == 0) red[t >> 6] = s;
    __syncthreads();
    if (t == 0) bval = red[0] + red[1] + red[2] + red[3];
    __syncthreads();
    float lse = mx + logf(bval);
#pragma unroll
    for (int j = 0; j < 16; ++j) out[t + 256 * j] = v[j] - lse;
}

extern "C" void kernel_launch(void* const* d_in, const int* in_sizes, int n_in,
                              void* d_out, int out_size, void* d_ws, size_t ws_size,
                              hipStream_t stream) {
    const int*   idx     = (const int*)  d_in[0];
    const float* hidden  = (const float*)d_in[1];
    // d_in[2] (encoder_output) unused by the forward pass
    const float* enc     = (const float*)d_in[3];
    const float* emb_W   = (const float*)d_in[4];
    const float* att_W   = (const float*)d_in[5];
    const float* att_b   = (const float*)d_in[6];
    const float* atc_W   = (const float*)d_in[7];
    const float* atc_b   = (const float*)d_in[8];
    const float* W_ih    = (const float*)d_in[9];
    const float* W_hh    = (const float*)d_in[10];
    const float* b_ih    = (const float*)d_in[11];
    const float* b_hh    = (const float*)d_in[12];
    const float* out_W   = (const float*)d_in[13];
    const float* out_b   = (const float*)d_in[14];

    float* out    = (float*)d_out;        // [0, 4096)   log_softmax
    float* h_new  = out + OO;             // [4096, 8192) new hidden
    float* atw    = out + OO + HH;        // [8192,10240) attention weights

    float* ws         = (float*)d_ws;
    float* at_in      = ws;               // 8192
    float* comb       = ws + 8192;        // 8192 (emb | atapplied)
    float* att_logits = ws + 16384;       // 2048
    float* x          = ws + 18432;       // 4096
    float* gi         = ws + 22528;       // 12288
    float* gh         = ws + 34816;       // 12288
    float* out_logits = ws + 47104;       // 4096
    float* part       = ws + 51200;       // 128*4096

    size_t need = (size_t)(51200 + 128 * HH) * sizeof(float);

    // 1. gather emb row, build concat inputs
    k_setup<<<HH / 256, 256, 0, stream>>>(idx, emb_W, hidden, at_in, comb);
    // 2. attention logits: [2048,8192] GEMV
    k_gemv<2 * HH, 0><<<MAXLEN / 4, 256, 0, stream>>>(att_W, at_in, att_b, att_logits, MAXLEN);
    // 3. softmax -> atweights (third output, also consumed below)
    k_softmax2048<<<1, 256, 0, stream>>>(att_logits, atw);
    // 4. atapplied = atweights @ encoder_outputs -> comb[4096..]
    if (ws_size >= need) {
        k_attapply_part<<<MAXLEN / 16, 256, 0, stream>>>(atw, enc, part);
        k_attapply_red<<<HH / 256, 256, 0, stream>>>(part, comb + HH);
    } else {
        k_attapply_atomic<<<MAXLEN / 16, 256, 0, stream>>>(atw, enc, comb + HH);
    }
    // 5. x = relu(atc_W @ comb + atc_b): [4096,8192] GEMV
    k_gemv<2 * HH, 1><<<HH / 4, 256, 0, stream>>>(atc_W, comb, atc_b, x, HH);
    // 6. GRU input/hidden gates: 2x [12288,4096] GEMV
    k_gemv<HH, 0><<<3 * HH / 4, 256, 0, stream>>>(W_ih, x, b_ih, gi, 3 * HH);
    k_gemv<HH, 0><<<3 * HH / 4, 256, 0, stream>>>(W_hh, hidden, b_hh, gh, 3 * HH);
    // 7. gate math -> h_new (second output)
    k_gru<<<HH / 256, 256, 0, stream>>>(gi, gh, hidden, h_new);
    // 8. out logits: [4096,4096] GEMV
    k_gemv<HH, 0><<<HH / 4, 256, 0, stream>>>(out_W, h_new, out_b, out_logits, HH);
    // 9. log_softmax -> out (first output)
    k_logsoftmax4096<<<1, 256, 0, stream>>>(out_logits, out);
}

// Round 2
// 139.881 us; speedup vs baseline: 1.1796x; 1.1796x over previous
//
#include <hip/hip_runtime.h>
#include <math.h>

#define HH 4096
#define OO 4096
#define MAXLEN 2048

__device__ inline float wave_sum(float v) {
#pragma unroll
    for (int off = 32; off; off >>= 1) v += __shfl_down(v, off, 64);
    return v;
}
__device__ inline float wave_max(float v) {
#pragma unroll
    for (int off = 32; off; off >>= 1) v = fmaxf(v, __shfl_down(v, off, 64));
    return v;
}

// sum 256 per-thread partials; result valid in all threads
__device__ inline float block_sum(float acc) {
    __shared__ float red[4];
    acc = wave_sum(acc);
    int t = threadIdx.x;
    if ((t & 63) == 0) red[t >> 6] = acc;
    __syncthreads();
    return red[0] + red[1] + red[2] + red[3];
}

// per-thread partial dot of one 1024*NV-float row segment; 256 threads/block
template <int NV>
__device__ inline float dot_row(const float4* __restrict__ W4, const float4* __restrict__ x4) {
    int t = threadIdx.x;
    float acc = 0.f;
#pragma unroll
    for (int j = 0; j < NV; ++j) {
        float4 w = W4[t + 256 * j];
        float4 v = x4[t + 256 * j];
        acc = fmaf(w.x, v.x, acc);
        acc = fmaf(w.y, v.y, acc);
        acc = fmaf(w.z, v.z, acc);
        acc = fmaf(w.w, v.w, acc);
    }
    return acc;
}

// fused: att logits (blocks 0..2047, L=8192 over [emb|hidden]) and
//        gh = W_hh @ hidden (blocks 2048..14335, L=4096)
__global__ void k_stage1(const float* __restrict__ att_W, const float* __restrict__ att_b,
                         const float* __restrict__ emb_W, const int* __restrict__ idx,
                         const float* __restrict__ hidden,
                         const float* __restrict__ W_hh, const float* __restrict__ b_hh,
                         float* __restrict__ attlog, float* __restrict__ gh) {
    int blk = blockIdx.x;
    if (blk < MAXLEN) {
        const float* emb = emb_W + (size_t)idx[0] * HH;
        const float* Wr = att_W + (size_t)blk * (2 * HH);
        float acc = dot_row<4>((const float4*)Wr, (const float4*)emb)
                  + dot_row<4>((const float4*)(Wr + HH), (const float4*)hidden);
        float tot = block_sum(acc);
        if (threadIdx.x == 0) attlog[blk] = tot + att_b[blk];
    } else {
        int r = blk - MAXLEN;
        const float* Wr = W_hh + (size_t)r * HH;
        float acc = dot_row<4>((const float4*)Wr, (const float4*)hidden);
        float tot = block_sum(acc);
        if (threadIdx.x == 0) gh[r] = tot + b_hh[r];
    }
}

// x = relu(atc_W @ [emb | atap] + atc_b), block per row
__global__ void k_atc(const float* __restrict__ atc_W, const float* __restrict__ atc_b,
                      const float* __restrict__ emb_W, const int* __restrict__ idx,
                      const float* __restrict__ atap, float* __restrict__ x) {
    int r = blockIdx.x;
    const float* emb = emb_W + (size_t)idx[0] * HH;
    const float* Wr = atc_W + (size_t)r * (2 * HH);
    float acc = dot_row<4>((const float4*)Wr, (const float4*)emb)
              + dot_row<4>((const float4*)(Wr + HH), (const float4*)atap);
    float tot = block_sum(acc);
    if (threadIdx.x == 0) x[r] = fmaxf(tot + atc_b[r], 0.f);
}

// y[r] = W[r,:]·xv + b[r], L = 4096, block per row
__global__ void k_gemv4k(const float* __restrict__ W, const float* __restrict__ xv,
                         const float* __restrict__ b, float* __restrict__ y) {
    int r = blockIdx.x;
    const float* Wr = W + (size_t)r * HH;
    float acc = dot_row<4>((const float4*)Wr, (const float4*)xv);
    float tot = block_sum(acc);
    if (threadIdx.x == 0) y[r] = tot + b[r];
}

// softmax over 2048 logits, one block of 256 threads
__global__ void k_softmax2048(const float* __restrict__ l, float* __restrict__ w) {
    __shared__ float red[4];
    __shared__ float bval;
    int t = threadIdx.x;
    float v[8];
    float m = -INFINITY;
#pragma unroll
    for (int j = 0; j < 8; ++j) { v[j] = l[t + 256 * j]; m = fmaxf(m, v[j]); }
    m = wave_max(m);
    if ((t & 63) == 0) red[t >> 6] = m;
    __syncthreads();
    if (t == 0) bval = fmaxf(fmaxf(red[0], red[1]), fmaxf(red[2], red[3]));
    __syncthreads();
    float mx = bval;
    float s = 0.f;
#pragma unroll
    for (int j = 0; j < 8; ++j) { v[j] = expf(v[j] - mx); s += v[j]; }
    s = wave_sum(s);
    if ((t & 63) == 0) red[t >> 6] = s;
    __syncthreads();
    if (t == 0) bval = red[0] + red[1] + red[2] + red[3];
    __syncthreads();
    float inv = 1.0f / bval;
#pragma unroll
    for (int j = 0; j < 8; ++j) w[t + 256 * j] = v[j] * inv;
}

// partial weighted column-sums: block = (chunk of 32 rows) x (col quarter)
__global__ void k_attapply_part(const float* __restrict__ w, const float* __restrict__ E,
                                float* __restrict__ part) {
    int q = blockIdx.x & 3;
    int c = blockIdx.x >> 2;              // 0..63
    int t = threadIdx.x;
    int col4 = q * 256 + t;               // float4 index within row
    float4 acc = {0.f, 0.f, 0.f, 0.f};
#pragma unroll 8
    for (int rr = 0; rr < 32; ++rr) {
        int m = c * 32 + rr;
        float wm = w[m];
        float4 e = ((const float4*)(E + (size_t)m * HH))[col4];
        acc.x = fmaf(wm, e.x, acc.x);
        acc.y = fmaf(wm, e.y, acc.y);
        acc.z = fmaf(wm, e.z, acc.z);
        acc.w = fmaf(wm, e.w, acc.w);
    }
    ((float4*)(part + (size_t)c * HH))[col4] = acc;
}

// deterministic reduce of 64 partial rows -> atap
__global__ void k_attapply_red(const float* __restrict__ part, float* __restrict__ atap) {
    int j = blockIdx.x * 256 + threadIdx.x;
    float s = 0.f;
#pragma unroll 8
    for (int c = 0; c < 64; ++c) s += part[(size_t)c * HH + j];
    atap[j] = s;
}

// GRU gate math; h_new written straight into d_out[O..O+H)
__global__ void k_gru(const float* __restrict__ gi, const float* __restrict__ gh,
                      const float* __restrict__ h, float* __restrict__ h_new) {
    int i = blockIdx.x * 256 + threadIdx.x;
    float r = 1.f / (1.f + expf(-(gi[i] + gh[i])));
    float z = 1.f / (1.f + expf(-(gi[HH + i] + gh[HH + i])));
    float n = tanhf(gi[2 * HH + i] + r * gh[2 * HH + i]);
    h_new[i] = (1.f - z) * n + z * h[i];
}

// log_softmax over 4096, one block of 256 threads
__global__ void k_logsoftmax4096(const float* __restrict__ l, float* __restrict__ out) {
    __shared__ float red[4];
    __shared__ float bval;
    int t = threadIdx.x;
    float v[16];
    float m = -INFINITY;
#pragma unroll
    for (int j = 0; j < 16; ++j) { v[j] = l[t + 256 * j]; m = fmaxf(m, v[j]); }
    m = wave_max(m);
    if ((t & 63) == 0) red[t >> 6] = m;
    __syncthreads();
    if (t == 0) bval = fmaxf(fmaxf(red[0], red[1]), fmaxf(red[2], red[3]));
    __syncthreads();
    float mx = bval;
    float s = 0.f;
#pragma unroll
    for (int j = 0; j < 16; ++j) s += expf(v[j] - mx);
    s = wave_sum(s);
    if ((t & 63) == 0) red[t >> 6] = s;
    __syncthreads();
    if (t == 0) bval = red[0] + red[1] + red[2] + red[3];
    __syncthreads();
    float lse = mx + logf(bval);
#pragma unroll
    for (int j = 0; j < 16; ++j) out[t + 256 * j] = v[j] - lse;
}

extern "C" void kernel_launch(void* const* d_in, const int* in_sizes, int n_in,
                              void* d_out, int out_size, void* d_ws, size_t ws_size,
                              hipStream_t stream) {
    const int*   idx     = (const int*)  d_in[0];
    const float* hidden  = (const float*)d_in[1];
    // d_in[2] (encoder_output) unused by the forward pass
    const float* enc     = (const float*)d_in[3];
    const float* emb_W   = (const float*)d_in[4];
    const float* att_W   = (const float*)d_in[5];
    const float* att_b   = (const float*)d_in[6];
    const float* atc_W   = (const float*)d_in[7];
    const float* atc_b   = (const float*)d_in[8];
    const float* W_ih    = (const float*)d_in[9];
    const float* W_hh    = (const float*)d_in[10];
    const float* b_ih    = (const float*)d_in[11];
    const float* b_hh    = (const float*)d_in[12];
    const float* out_W   = (const float*)d_in[13];
    const float* out_b   = (const float*)d_in[14];

    float* out    = (float*)d_out;        // [0, 4096)    log_softmax
    float* h_new  = out + OO;             // [4096, 8192) new hidden
    float* atw    = out + OO + HH;        // [8192,10240) attention weights

    float* ws         = (float*)d_ws;
    float* attlog     = ws;               // 2048
    float* atap       = ws + 2048;        // 4096
    float* x          = ws + 6144;        // 4096
    float* gi         = ws + 10240;       // 12288
    float* gh         = ws + 22528;       // 12288
    float* outlog     = ws + 34816;       // 4096
    float* part       = ws + 38912;       // 64*4096

    // 1. att logits (2048 blocks) || gh = W_hh@hidden (12288 blocks), fused
    k_stage1<<<MAXLEN + 3 * HH, 256, 0, stream>>>(att_W, att_b, emb_W, idx, hidden,
                                                  W_hh, b_hh, attlog, gh);
    // 2. softmax -> atweights (third output, also consumed below)
    k_softmax2048<<<1, 256, 0, stream>>>(attlog, atw);
    // 3. atapplied = atweights @ encoder_outputs
    k_attapply_part<<<256, 256, 0, stream>>>(atw, enc, part);
    k_attapply_red<<<16, 256, 0, stream>>>(part, atap);
    // 4. x = relu(atc_W @ [emb|atap] + atc_b)
    k_atc<<<HH, 256, 0, stream>>>(atc_W, atc_b, emb_W, idx, atap, x);
    // 5. gi = W_ih @ x + b_ih
    k_gemv4k<<<3 * HH, 256, 0, stream>>>(W_ih, x, b_ih, gi);
    // 6. gate math -> h_new (second output)
    k_gru<<<HH / 256, 256, 0, stream>>>(gi, gh, hidden, h_new);
    // 7. out logits
    k_gemv4k<<<HH, 256, 0, stream>>>(out_W, h_new, out_b, outlog);
    // 8. log_softmax -> out (first output)
    k_logsoftmax4096<<<1, 256, 0, stream>>>(outlog, out);
}

// Round 3
// 136.054 us; speedup vs baseline: 1.2127x; 1.0281x over previous
//
#include <hip/hip_runtime.h>
#include <math.h>

#define HH 4096
#define OO 4096
#define MAXLEN 2048

__device__ inline float wave_sum(float v) {
#pragma unroll
    for (int off = 32; off; off >>= 1) v += __shfl_down(v, off, 64);
    return v;
}
__device__ inline float wave_max(float v) {
#pragma unroll
    for (int off = 32; off; off >>= 1) v = fmaxf(v, __shfl_down(v, off, 64));
    return v;
}

// sum 256 per-thread partials; result valid in all threads
__device__ inline float block_sum(float acc) {
    __shared__ float red[4];
    acc = wave_sum(acc);
    int t = threadIdx.x;
    if ((t & 63) == 0) red[t >> 6] = acc;
    __syncthreads();
    return red[0] + red[1] + red[2] + red[3];
}

// per-thread partial dot over 1024*NV floats; 256 threads/block
template <int NV>
__device__ inline float dot_row(const float4* __restrict__ W4, const float4* __restrict__ x4) {
    int t = threadIdx.x;
    float acc = 0.f;
#pragma unroll
    for (int j = 0; j < NV; ++j) {
        float4 w = W4[t + 256 * j];
        float4 v = x4[t + 256 * j];
        acc = fmaf(w.x, v.x, acc);
        acc = fmaf(w.y, v.y, acc);
        acc = fmaf(w.z, v.z, acc);
        acc = fmaf(w.w, v.w, acc);
    }
    return acc;
}

// attention logits: block per row, L=8192 over [emb | hidden]
__global__ void k_att(const float* __restrict__ att_W, const float* __restrict__ att_b,
                      const float* __restrict__ emb_W, const int* __restrict__ idx,
                      const float* __restrict__ hidden, float* __restrict__ attlog) {
    int r = blockIdx.x;
    const float* emb = emb_W + (size_t)idx[0] * HH;
    const float* Wr = att_W + (size_t)r * (2 * HH);
    float acc = dot_row<4>((const float4*)Wr, (const float4*)emb)
              + dot_row<4>((const float4*)(Wr + HH), (const float4*)hidden);
    float tot = block_sum(acc);
    if (threadIdx.x == 0) attlog[r] = tot + att_b[r];
}

// fused softmax + weighted partial column-sums.
// 256 blocks = 64 row-chunks (32 rows) x 4 col-quarters. Each block
// redundantly computes softmax stats from attlog (8KB, L2-resident).
// Blocks with q==0 also write atw (the third output).
__global__ void k_smpart(const float* __restrict__ attlog, const float* __restrict__ E,
                         float* __restrict__ part, float* __restrict__ atw) {
    __shared__ float red[4];
    __shared__ float s_mx, s_sum;
    int t = threadIdx.x;
    int q = blockIdx.x & 3;
    int c = blockIdx.x >> 2;              // 0..63

    // softmax stats over all 2048 logits
    float v[8];
    float m = -INFINITY;
#pragma unroll
    for (int j = 0; j < 8; ++j) { v[j] = attlog[t + 256 * j]; m = fmaxf(m, v[j]); }
    m = wave_max(m);
    if ((t & 63) == 0) red[t >> 6] = m;
    __syncthreads();
    if (t == 0) s_mx = fmaxf(fmaxf(red[0], red[1]), fmaxf(red[2], red[3]));
    __syncthreads();
    float mx = s_mx;
    float s = 0.f;
#pragma unroll
    for (int j = 0; j < 8; ++j) s += expf(v[j] - mx);
    s = wave_sum(s);
    __syncthreads();                       // red reuse
    if ((t & 63) == 0) red[t >> 6] = s;
    __syncthreads();
    if (t == 0) s_sum = red[0] + red[1] + red[2] + red[3];
    __syncthreads();
    float inv = 1.0f / s_sum;

    // weighted partial sums over this chunk's 32 rows, this quarter's 1024 cols
    int col4 = q * 256 + t;
    float4 acc = {0.f, 0.f, 0.f, 0.f};
#pragma unroll 8
    for (int rr = 0; rr < 32; ++rr) {
        int mrow = c * 32 + rr;
        float wm = expf(attlog[mrow] - mx) * inv;
        float4 e = ((const float4*)(E + (size_t)mrow * HH))[col4];
        acc.x = fmaf(wm, e.x, acc.x);
        acc.y = fmaf(wm, e.y, acc.y);
        acc.z = fmaf(wm, e.z, acc.z);
        acc.w = fmaf(wm, e.w, acc.w);
    }
    ((float4*)(part + (size_t)c * HH))[col4] = acc;

    if (q == 0 && t < 32) {
        int mrow = c * 32 + t;
        atw[mrow] = expf(attlog[mrow] - mx) * inv;
    }
}

// deterministic reduce of 64 partial rows -> atap
__global__ void k_red(const float* __restrict__ part, float* __restrict__ atap) {
    int j = blockIdx.x * 256 + threadIdx.x;
    float s = 0.f;
#pragma unroll 8
    for (int c = 0; c < 64; ++c) s += part[(size_t)c * HH + j];
    atap[j] = s;
}

// x = relu(atc_W @ [emb | atap] + atc_b), block per row
__global__ void k_atc(const float* __restrict__ atc_W, const float* __restrict__ atc_b,
                      const float* __restrict__ emb_W, const int* __restrict__ idx,
                      const float* __restrict__ atap, float* __restrict__ x) {
    int r = blockIdx.x;
    const float* emb = emb_W + (size_t)idx[0] * HH;
    const float* Wr = atc_W + (size_t)r * (2 * HH);
    float acc = dot_row<4>((const float4*)Wr, (const float4*)emb)
              + dot_row<4>((const float4*)(Wr + HH), (const float4*)atap);
    float tot = block_sum(acc);
    if (threadIdx.x == 0) x[r] = fmaxf(tot + atc_b[r], 0.f);
}

// fused GRU: block r computes all 6 row-dots (W_ih{r,H+r,2H+r}·x,
// W_hh{r,H+r,2H+r}·h) + gate math -> h_new[r]. 96KB streamed per block.
__global__ void k_giGru(const float* __restrict__ W_ih, const float* __restrict__ b_ih,
                        const float* __restrict__ W_hh, const float* __restrict__ b_hh,
                        const float* __restrict__ x, const float* __restrict__ h,
                        float* __restrict__ h_new) {
    __shared__ float red[6][4];
    int r = blockIdx.x;
    int t = threadIdx.x, wid = t >> 6, lane = t & 63;
    const float4* xv = (const float4*)x;
    const float4* hv = (const float4*)h;
    float a[6];
    a[0] = dot_row<4>((const float4*)(W_ih + (size_t)r * HH), xv);
    a[1] = dot_row<4>((const float4*)(W_ih + (size_t)(HH + r) * HH), xv);
    a[2] = dot_row<4>((const float4*)(W_ih + (size_t)(2 * HH + r) * HH), xv);
    a[3] = dot_row<4>((const float4*)(W_hh + (size_t)r * HH), hv);
    a[4] = dot_row<4>((const float4*)(W_hh + (size_t)(HH + r) * HH), hv);
    a[5] = dot_row<4>((const float4*)(W_hh + (size_t)(2 * HH + r) * HH), hv);
#pragma unroll
    for (int k = 0; k < 6; ++k) {
        a[k] = wave_sum(a[k]);
        if (lane == 0) red[k][wid] = a[k];
    }
    __syncthreads();
    if (t == 0) {
        float g[6];
#pragma unroll
        for (int k = 0; k < 6; ++k) g[k] = red[k][0] + red[k][1] + red[k][2] + red[k][3];
        float i_r = g[0] + b_ih[r];
        float i_z = g[1] + b_ih[HH + r];
        float i_n = g[2] + b_ih[2 * HH + r];
        float h_r = g[3] + b_hh[r];
        float h_z = g[4] + b_hh[HH + r];
        float h_n = g[5] + b_hh[2 * HH + r];
        float rg = 1.f / (1.f + expf(-(i_r + h_r)));
        float z  = 1.f / (1.f + expf(-(i_z + h_z)));
        float n  = tanhf(i_n + rg * h_n);
        h_new[r] = (1.f - z) * n + z * h[r];
    }
}

// y[r] = W[r,:]·xv + b[r], L = 4096, block per row
__global__ void k_gemv4k(const float* __restrict__ W, const float* __restrict__ xv,
                         const float* __restrict__ b, float* __restrict__ y) {
    int r = blockIdx.x;
    const float* Wr = W + (size_t)r * HH;
    float acc = dot_row<4>((const float4*)Wr, (const float4*)xv);
    float tot = block_sum(acc);
    if (threadIdx.x == 0) y[r] = tot + b[r];
}

// log_softmax over 4096, one block of 256 threads
__global__ void k_logsoftmax4096(const float* __restrict__ l, float* __restrict__ out) {
    __shared__ float red[4];
    __shared__ float bval;
    int t = threadIdx.x;
    float v[16];
    float m = -INFINITY;
#pragma unroll
    for (int j = 0; j < 16; ++j) { v[j] = l[t + 256 * j]; m = fmaxf(m, v[j]); }
    m = wave_max(m);
    if ((t & 63) == 0) red[t >> 6] = m;
    __syncthreads();
    if (t == 0) bval = fmaxf(fmaxf(red[0], red[1]), fmaxf(red[2], red[3]));
    __syncthreads();
    float mx = bval;
    float s = 0.f;
#pragma unroll
    for (int j = 0; j < 16; ++j) s += expf(v[j] - mx);
    s = wave_sum(s);
    __syncthreads();
    if ((t & 63) == 0) red[t >> 6] = s;
    __syncthreads();
    if (t == 0) bval = red[0] + red[1] + red[2] + red[3];
    __syncthreads();
    float lse = mx + logf(bval);
#pragma unroll
    for (int j = 0; j < 16; ++j) out[t + 256 * j] = v[j] - lse;
}

extern "C" void kernel_launch(void* const* d_in, const int* in_sizes, int n_in,
                              void* d_out, int out_size, void* d_ws, size_t ws_size,
                              hipStream_t stream) {
    const int*   idx     = (const int*)  d_in[0];
    const float* hidden  = (const float*)d_in[1];
    // d_in[2] (encoder_output) unused by the forward pass
    const float* enc     = (const float*)d_in[3];
    const float* emb_W   = (const float*)d_in[4];
    const float* att_W   = (const float*)d_in[5];
    const float* att_b   = (const float*)d_in[6];
    const float* atc_W   = (const float*)d_in[7];
    const float* atc_b   = (const float*)d_in[8];
    const float* W_ih    = (const float*)d_in[9];
    const float* W_hh    = (const float*)d_in[10];
    const float* b_ih    = (const float*)d_in[11];
    const float* b_hh    = (const float*)d_in[12];
    const float* out_W   = (const float*)d_in[13];
    const float* out_b   = (const float*)d_in[14];

    float* out    = (float*)d_out;        // [0, 4096)    log_softmax
    float* h_new  = out + OO;             // [4096, 8192) new hidden
    float* atw    = out + OO + HH;        // [8192,10240) attention weights

    float* ws         = (float*)d_ws;
    float* attlog     = ws;               // 2048
    float* atap       = ws + 2048;        // 4096
    float* x          = ws + 6144;        // 4096
    float* outlog     = ws + 10240;       // 4096
    float* part       = ws + 14336;       // 64*4096

    // 1. att logits
    k_att<<<MAXLEN, 256, 0, stream>>>(att_W, att_b, emb_W, idx, hidden, attlog);
    // 2. fused softmax + weighted partial column-sums (also writes atw output)
    k_smpart<<<256, 256, 0, stream>>>(attlog, enc, part, atw);
    // 3. deterministic reduce -> atap
    k_red<<<16, 256, 0, stream>>>(part, atap);
    // 4. x = relu(atc_W @ [emb|atap] + atc_b)
    k_atc<<<HH, 256, 0, stream>>>(atc_W, atc_b, emb_W, idx, atap, x);
    // 5. fused GRU (both weight matrices + gate math) -> h_new output
    k_giGru<<<HH, 256, 0, stream>>>(W_ih, b_ih, W_hh, b_hh, x, hidden, h_new);
    // 6. out logits
    k_gemv4k<<<HH, 256, 0, stream>>>(out_W, h_new, out_b, outlog);
    // 7. log_softmax -> out (first output)
    k_logsoftmax4096<<<1, 256, 0, stream>>>(outlog, out);
}